// Round 1
// baseline (277.333 us; speedup 1.0000x reference)
//
#include <hip/hip_runtime.h>

// ---------------------------------------------------------------------------
// Kernel 1: exclusive prefix sum of lengths -> offsets (general ragged case).
// Single block, 1024 threads, handles up to 2048 segments (2 per thread).
// ---------------------------------------------------------------------------
__global__ __launch_bounds__(1024) void offsets_kernel(const int* __restrict__ lengths,
                                                       int* __restrict__ offsets,
                                                       int n_seg) {
    int t = threadIdx.x;
    int i0 = 2 * t, i1 = 2 * t + 1;
    int a = (i0 < n_seg) ? lengths[i0] : 0;
    int b = (i1 < n_seg) ? lengths[i1] : 0;
    int s = a + b;

    int lane = t & 63;
    int wave = t >> 6;

    // inclusive wave scan (64 lanes)
    int v = s;
    #pragma unroll
    for (int d = 1; d < 64; d <<= 1) {
        int u = __shfl_up(v, d, 64);
        if (lane >= d) v += u;
    }

    __shared__ int wsum[16];
    if (lane == 63) wsum[wave] = v;
    __syncthreads();

    if (wave == 0 && lane < 16) {
        int w = wsum[lane];
        #pragma unroll
        for (int d = 1; d < 16; d <<= 1) {
            int u = __shfl_up(w, d, 64);
            if (lane >= d) w += u;
        }
        wsum[lane] = w;
    }
    __syncthreads();

    int base = (wave > 0) ? wsum[wave - 1] : 0;
    int incl = base + v;         // inclusive sum through pair t
    int excl = incl - s;         // exclusive offset before element 2t
    if (i0 < n_seg) offsets[i0] = excl;
    if (i1 < n_seg) offsets[i1] = excl + a;
}

// ---------------------------------------------------------------------------
// Kernel 2: one block per segment. Streams the segment's L*129 output floats.
// col 0 -> (row+1)/L, cols 1..128 -> x[row*128 + col-1].
// Vectorized float4 store path when the segment's flat output range is
// 16B-aligned and a multiple of 4 elements; scalar fallback otherwise.
// ---------------------------------------------------------------------------
__global__ __launch_bounds__(256) void emb_kernel(const float* __restrict__ x,
                                                  const int* __restrict__ lengths,
                                                  const int* __restrict__ offsets,
                                                  float* __restrict__ out) {
    const int s = blockIdx.x;
    const int off = offsets[s];
    const int L = lengths[s];
    if (L <= 0) return;
    const float invL = 1.0f / (float)L;

    const float* __restrict__ xs = x + (long long)off * 128;
    float* __restrict__ os = out + (long long)off * 129;

    const int E = L * 129;                   // flat elements this segment
    const long long seg_elem0 = (long long)off * 129;
    const bool vec = ((seg_elem0 & 3LL) == 0) && ((E & 3) == 0);

    if (vec) {
        float4* __restrict__ o4 = (float4*)os;
        const int n4 = E >> 2;
        for (int i = threadIdx.x; i < n4; i += blockDim.x) {
            const int e = i << 2;
            const int row = e / 129;          // compiler emits magic-mul
            const int col = e - row * 129;
            float vals[4];
            #pragma unroll
            for (int k = 0; k < 4; ++k) {
                int r = row, c = col + k;
                if (c >= 129) { c -= 129; r += 1; }   // at most one row wrap
                vals[k] = (c == 0) ? (float)(r + 1) * invL
                                   : xs[r * 128 + (c - 1)];
            }
            float4 v;
            v.x = vals[0]; v.y = vals[1]; v.z = vals[2]; v.w = vals[3];
            o4[i] = v;
        }
    } else {
        for (int e = threadIdx.x; e < E; e += blockDim.x) {
            const int row = e / 129;
            const int col = e - row * 129;
            os[e] = (col == 0) ? (float)(row + 1) * invL
                               : xs[row * 128 + (col - 1)];
        }
    }
}

extern "C" void kernel_launch(void* const* d_in, const int* in_sizes, int n_in,
                              void* d_out, int out_size, void* d_ws, size_t ws_size,
                              hipStream_t stream) {
    const float* x = (const float*)d_in[0];
    const int* lengths = (const int*)d_in[1];
    const int n_seg = in_sizes[1];

    int* offsets = (int*)d_ws;               // n_seg ints of scratch

    offsets_kernel<<<1, 1024, 0, stream>>>(lengths, offsets, n_seg);
    emb_kernel<<<n_seg, 256, 0, stream>>>(x, lengths, offsets, (float*)d_out);
}

// Round 2
// 237.695 us; speedup vs baseline: 1.1668x; 1.1668x over previous
//
#include <hip/hip_runtime.h>

// ---------------------------------------------------------------------------
// Kernel 1: exclusive prefix sum of lengths -> offsets (general ragged case).
// Single block, 1024 threads, handles up to 2048 segments (2 per thread).
// ---------------------------------------------------------------------------
__global__ __launch_bounds__(1024) void offsets_kernel(const int* __restrict__ lengths,
                                                       int* __restrict__ offsets,
                                                       int n_seg) {
    int t = threadIdx.x;
    int i0 = 2 * t, i1 = 2 * t + 1;
    int a = (i0 < n_seg) ? lengths[i0] : 0;
    int b = (i1 < n_seg) ? lengths[i1] : 0;
    int s = a + b;

    int lane = t & 63;
    int wave = t >> 6;

    int v = s;
    #pragma unroll
    for (int d = 1; d < 64; d <<= 1) {
        int u = __shfl_up(v, d, 64);
        if (lane >= d) v += u;
    }

    __shared__ int wsum[16];
    if (lane == 63) wsum[wave] = v;
    __syncthreads();

    if (wave == 0 && lane < 16) {
        int w = wsum[lane];
        #pragma unroll
        for (int d = 1; d < 16; d <<= 1) {
            int u = __shfl_up(w, d, 64);
            if (lane >= d) w += u;
        }
        wsum[lane] = w;
    }
    __syncthreads();

    int base = (wave > 0) ? wsum[wave - 1] : 0;
    int incl = base + v;
    int excl = incl - s;
    if (i0 < n_seg) offsets[i0] = excl;
    if (i1 < n_seg) offsets[i1] = excl + a;
}

// ---------------------------------------------------------------------------
// Kernel 2: one block per segment. LDS-staged: per 32-row tile, stage the
// OUTPUT-layout tile (32*129 floats) in LDS, then stream it out with aligned
// float4 stores. Input loads are aligned float4; the +1 column shift is
// absorbed by the LDS scatter (ds_write_b32, ~8-way conflicts, cheap).
// Phase-2 reads are aligned ds_read_b128, conflict-free.
// ---------------------------------------------------------------------------
__global__ __launch_bounds__(256) void emb_kernel(const float* __restrict__ x,
                                                  const int* __restrict__ lengths,
                                                  const int* __restrict__ offsets,
                                                  float* __restrict__ out) {
    __shared__ alignas(16) float lt[32 * 129];   // 4128 floats = 16.125 KB

    const int s = blockIdx.x;
    const int off = offsets[s];
    const int L = lengths[s];
    if (L <= 0) return;
    const float invL = 1.0f / (float)L;

    const float* __restrict__ xs = x + (size_t)off * 128;
    float* __restrict__ os = out + (size_t)off * 129;
    const int tid = threadIdx.x;

    // Fast path requires out segment base (off*129 floats) 16B-aligned,
    // i.e. off % 4 == 0. Covers full 32-row tiles; tail handled scalar.
    const int full = ((off & 3) == 0) ? (L >> 5) : 0;

    for (int t = 0; t < full; ++t) {
        const float4* __restrict__ x4 = (const float4*)(xs + (size_t)t * 4096);

        // Phase 1: global (aligned f4) -> LDS scatter in output layout.
        #pragma unroll
        for (int p = 0; p < 4; ++p) {
            const int q = tid + 256 * p;         // f4 index within tile, 0..1023
            const float4 v = x4[q];
            const int lr = q >> 5;               // row in tile
            const int c4 = (q & 31) << 2;        // starting col within row
            float* dst = &lt[lr * 129 + 1 + c4];
            dst[0] = v.x; dst[1] = v.y; dst[2] = v.z; dst[3] = v.w;
        }
        if (tid < 32) {
            const int gr = t * 32 + tid;         // row within segment
            lt[tid * 129] = (float)(gr + 1) * invL;
        }
        __syncthreads();

        // Phase 2: LDS (aligned b128) -> global (aligned f4), pure stream.
        float4* __restrict__ o4 = (float4*)(os + (size_t)t * 4128);
        const float4* __restrict__ l4 = (const float4*)lt;
        #pragma unroll
        for (int p = 0; p < 5; ++p) {
            const int j = tid + 256 * p;         // 0..1031
            if (j < 1032) o4[j] = l4[j];
        }
        __syncthreads();
    }

    // Tail / unaligned fallback (generic ragged correctness).
    const int e0 = full * 4128;
    const int E = L * 129;
    for (int e = e0 + tid; e < E; e += 256) {
        const int row = e / 129;
        const int col = e - row * 129;
        os[e] = (col == 0) ? (float)(row + 1) * invL
                           : xs[row * 128 + (col - 1)];
    }
}

extern "C" void kernel_launch(void* const* d_in, const int* in_sizes, int n_in,
                              void* d_out, int out_size, void* d_ws, size_t ws_size,
                              hipStream_t stream) {
    const float* x = (const float*)d_in[0];
    const int* lengths = (const int*)d_in[1];
    const int n_seg = in_sizes[1];

    int* offsets = (int*)d_ws;

    offsets_kernel<<<1, 1024, 0, stream>>>(lengths, offsets, n_seg);
    emb_kernel<<<n_seg, 256, 0, stream>>>(x, lengths, offsets, (float*)d_out);
}